// Round 1
// baseline (87.600 us; speedup 1.0000x reference)
//
#include <hip/hip_runtime.h>

#define N_NODES 2048
#define F_IN 64
#define C_OUT 8
#define H_HID 32
#define G_NUM 16

// Kernel 1: f_sum[n,c] = sum_f ( relu(x[n,f]*W1[f,:]+b1[f,:]) . W2[f,c,:] + b2[f,c] )
// One block (1 wave, 64 lanes) per node; lane f handles feature f.
__global__ __launch_bounds__(64) void fsum_kernel(
    const float* __restrict__ x, const float* __restrict__ W1,
    const float* __restrict__ b1, const float* __restrict__ W2,
    const float* __restrict__ b2, float* __restrict__ fsum)
{
    const int n = blockIdx.x;
    const int f = threadIdx.x;   // 0..63
    const float xv = x[n * F_IN + f];

    float acc[C_OUT];
    #pragma unroll
    for (int c = 0; c < C_OUT; ++c) acc[c] = b2[f * C_OUT + c];

    #pragma unroll
    for (int h = 0; h < H_HID; ++h) {
        float hv = xv * W1[f * H_HID + h] + b1[f * H_HID + h];
        hv = hv > 0.0f ? hv : 0.0f;
        #pragma unroll
        for (int c = 0; c < C_OUT; ++c)
            acc[c] += hv * W2[(f * C_OUT + c) * H_HID + h];
    }

    // wave64 reduce over features
    #pragma unroll
    for (int c = 0; c < C_OUT; ++c) {
        float v = acc[c];
        for (int off = 32; off; off >>= 1) v += __shfl_down(v, off);
        if (f == 0) fsum[n * C_OUT + c] = v;
    }
}

// Kernel 2: per-graph [start,end) ranges (batch is sorted).
__global__ __launch_bounds__(64) void bounds_kernel(
    const int* __restrict__ batch, int* __restrict__ bounds)
{
    const int g = threadIdx.x;
    if (g >= G_NUM) return;
    int lt = 0, le = 0;
    for (int i = 0; i < N_NODES; ++i) {
        const int b = batch[i];
        lt += (b < g) ? 1 : 0;
        le += (b <= g) ? 1 : 0;
    }
    bounds[g] = lt;           // start
    bounds[G_NUM + g] = le;   // end
}

// Kernel 3: per-row i: out[i,c] = sum_{j in same graph} rho(i,j,c)/norm_safe * f_sum[j,c]
__global__ __launch_bounds__(128) void row_kernel(
    const float* __restrict__ dist, const float* __restrict__ norm,
    const int* __restrict__ batch, const int* __restrict__ bounds,
    const float* __restrict__ rW1, const float* __restrict__ rb1,
    const float* __restrict__ rW2, const float* __restrict__ rb2,
    const float* __restrict__ fsum, float* __restrict__ rowout)
{
    const int i = blockIdx.x;
    const int tid = threadIdx.x;
    const int g = batch[i];
    const int js = bounds[g];
    const int je = bounds[G_NUM + g];

    __shared__ float sW1[H_HID], sb1[H_HID], sW2[C_OUT * H_HID], sb2[C_OUT];
    if (tid < H_HID) { sW1[tid] = rW1[tid]; sb1[tid] = rb1[tid]; }
    if (tid < C_OUT) sb2[tid] = rb2[tid];
    for (int k = tid; k < C_OUT * H_HID; k += 128) sW2[k] = rW2[k];
    __syncthreads();

    float acc[C_OUT] = {0.f, 0.f, 0.f, 0.f, 0.f, 0.f, 0.f, 0.f};

    for (int j = js + tid; j < je; j += 128) {
        const float d  = dist[(long)i * N_NODES + j];
        const float s  = 1.0f / (1.0f + d);
        const float nv = norm[(long)i * N_NODES + j];
        const float invn = (nv == 0.0f) ? 1.0f : (1.0f / nv);

        float rho[C_OUT];
        #pragma unroll
        for (int c = 0; c < C_OUT; ++c) rho[c] = sb2[c];

        #pragma unroll
        for (int h = 0; h < H_HID; ++h) {
            float rh = s * sW1[h] + sb1[h];
            rh = rh > 0.0f ? rh : 0.0f;
            #pragma unroll
            for (int c = 0; c < C_OUT; ++c) rho[c] += rh * sW2[c * H_HID + h];
        }

        #pragma unroll
        for (int c = 0; c < C_OUT; ++c)
            acc[c] += rho[c] * invn * fsum[j * C_OUT + c];
    }

    // reduce across 2 waves
    __shared__ float red[2][C_OUT];
    const int lane = tid & 63, wv = tid >> 6;
    #pragma unroll
    for (int c = 0; c < C_OUT; ++c) {
        float v = acc[c];
        for (int off = 32; off; off >>= 1) v += __shfl_down(v, off);
        if (lane == 0) red[wv][c] = v;
    }
    __syncthreads();
    if (tid < C_OUT) rowout[i * C_OUT + tid] = red[0][tid] + red[1][tid];
}

// Kernel 4: graph_out[g,c] = sum_{i in graph g} rowout[i,c]  (deterministic order)
__global__ __launch_bounds__(64) void readout_kernel(
    const float* __restrict__ rowout, const int* __restrict__ bounds,
    float* __restrict__ out)
{
    const int g = blockIdx.x;
    const int tid = threadIdx.x;
    const int is = bounds[g];
    const int ie = bounds[G_NUM + g];

    float acc[C_OUT] = {0.f, 0.f, 0.f, 0.f, 0.f, 0.f, 0.f, 0.f};
    for (int i = is + tid; i < ie; i += 64) {
        #pragma unroll
        for (int c = 0; c < C_OUT; ++c) acc[c] += rowout[i * C_OUT + c];
    }

    #pragma unroll
    for (int c = 0; c < C_OUT; ++c) {
        float v = acc[c];
        for (int off = 32; off; off >>= 1) v += __shfl_down(v, off);
        if (tid == 0) out[g * C_OUT + c] = v;
    }
}

extern "C" void kernel_launch(void* const* d_in, const int* in_sizes, int n_in,
                              void* d_out, int out_size, void* d_ws, size_t ws_size,
                              hipStream_t stream)
{
    const float* x    = (const float*)d_in[0];
    const float* dist = (const float*)d_in[1];
    const float* norm = (const float*)d_in[2];
    const int*   batch= (const int*)d_in[3];
    const float* fsW1 = (const float*)d_in[4];
    const float* fsb1 = (const float*)d_in[5];
    const float* fsW2 = (const float*)d_in[6];
    const float* fsb2 = (const float*)d_in[7];
    const float* rW1  = (const float*)d_in[8];
    const float* rb1  = (const float*)d_in[9];
    const float* rW2  = (const float*)d_in[10];
    const float* rb2  = (const float*)d_in[11];
    float* out = (float*)d_out;

    float* fsum   = (float*)d_ws;                       // N*C floats
    float* rowout = fsum + N_NODES * C_OUT;             // N*C floats
    int*   bounds = (int*)(rowout + N_NODES * C_OUT);   // 2*G ints

    fsum_kernel<<<N_NODES, 64, 0, stream>>>(x, fsW1, fsb1, fsW2, fsb2, fsum);
    bounds_kernel<<<1, 64, 0, stream>>>(batch, bounds);
    row_kernel<<<N_NODES, 128, 0, stream>>>(dist, norm, batch, bounds,
                                            rW1, rb1, rW2, rb2, fsum, rowout);
    readout_kernel<<<G_NUM, 64, 0, stream>>>(rowout, bounds, out);
}

// Round 2
// 55.944 us; speedup vs baseline: 1.5658x; 1.5658x over previous
//
#include <hip/hip_runtime.h>

#define N_NODES 2048
#define F_IN 64
#define C_OUT 8
#define H_HID 32
#define G_NUM 16

// Kernel 1: f_sum[n,c] = sum_f ( relu(x[n,f]*W1[f,:]+b1[f,:]) . W2[f,c,:] + b2[f,c] )
// One block (1 wave, 64 lanes) per node; lane f handles feature f.
__global__ __launch_bounds__(64) void fsum_kernel(
    const float* __restrict__ x, const float* __restrict__ W1,
    const float* __restrict__ b1, const float* __restrict__ W2,
    const float* __restrict__ b2, float* __restrict__ fsum)
{
    const int n = blockIdx.x;
    const int f = threadIdx.x;   // 0..63
    const float xv = x[n * F_IN + f];

    float acc[C_OUT];
    #pragma unroll
    for (int c = 0; c < C_OUT; ++c) acc[c] = b2[f * C_OUT + c];

    #pragma unroll
    for (int h = 0; h < H_HID; ++h) {
        float hv = xv * W1[f * H_HID + h] + b1[f * H_HID + h];
        hv = hv > 0.0f ? hv : 0.0f;
        #pragma unroll
        for (int c = 0; c < C_OUT; ++c)
            acc[c] += hv * W2[(f * C_OUT + c) * H_HID + h];
    }

    // wave64 reduce over features
    #pragma unroll
    for (int c = 0; c < C_OUT; ++c) {
        float v = acc[c];
        for (int off = 32; off; off >>= 1) v += __shfl_down(v, off);
        if (f == 0) fsum[n * C_OUT + c] = v;
    }
}

// Kernel 2: parallel boundary detection (batch sorted, values in [0,G)).
// starts[g] = first index i with batch[i] >= g; starts[G] = N.
__global__ __launch_bounds__(256) void bounds_kernel(
    const int* __restrict__ batch, int* __restrict__ starts)
{
    const int i = blockIdx.x * 256 + threadIdx.x;
    if (i >= N_NODES) return;
    const int cur = batch[i];
    const int prev = (i == 0) ? -1 : batch[i - 1];
    for (int g = prev + 1; g <= cur; ++g) starts[g] = i;
    if (i == N_NODES - 1) {
        for (int g = cur + 1; g <= G_NUM; ++g) starts[g] = N_NODES;
    }
}

// Kernel 3: per-row i: out[i,c] = sum_{j in same graph} rho(i,j,c)/norm_safe * f_sum[j,c]
__global__ __launch_bounds__(128) void row_kernel(
    const float* __restrict__ dist, const float* __restrict__ norm,
    const int* __restrict__ batch, const int* __restrict__ starts,
    const float* __restrict__ rW1, const float* __restrict__ rb1,
    const float* __restrict__ rW2, const float* __restrict__ rb2,
    const float* __restrict__ fsum, float* __restrict__ rowout)
{
    const int i = blockIdx.x;
    const int tid = threadIdx.x;
    const int g = batch[i];
    const int js = starts[g];
    const int je = starts[g + 1];

    __shared__ float sW1[H_HID], sb1[H_HID], sW2[C_OUT * H_HID], sb2[C_OUT];
    if (tid < H_HID) { sW1[tid] = rW1[tid]; sb1[tid] = rb1[tid]; }
    if (tid < C_OUT) sb2[tid] = rb2[tid];
    for (int k = tid; k < C_OUT * H_HID; k += 128) sW2[k] = rW2[k];
    __syncthreads();

    float acc[C_OUT] = {0.f, 0.f, 0.f, 0.f, 0.f, 0.f, 0.f, 0.f};

    for (int j = js + tid; j < je; j += 128) {
        const float d  = dist[(long)i * N_NODES + j];
        const float s  = 1.0f / (1.0f + d);
        const float nv = norm[(long)i * N_NODES + j];
        const float invn = (nv == 0.0f) ? 1.0f : (1.0f / nv);

        float rho[C_OUT];
        #pragma unroll
        for (int c = 0; c < C_OUT; ++c) rho[c] = sb2[c];

        #pragma unroll
        for (int h = 0; h < H_HID; ++h) {
            float rh = s * sW1[h] + sb1[h];
            rh = rh > 0.0f ? rh : 0.0f;
            #pragma unroll
            for (int c = 0; c < C_OUT; ++c) rho[c] += rh * sW2[c * H_HID + h];
        }

        #pragma unroll
        for (int c = 0; c < C_OUT; ++c)
            acc[c] += rho[c] * invn * fsum[j * C_OUT + c];
    }

    // reduce across 2 waves
    __shared__ float red[2][C_OUT];
    const int lane = tid & 63, wv = tid >> 6;
    #pragma unroll
    for (int c = 0; c < C_OUT; ++c) {
        float v = acc[c];
        for (int off = 32; off; off >>= 1) v += __shfl_down(v, off);
        if (lane == 0) red[wv][c] = v;
    }
    __syncthreads();
    if (tid < C_OUT) rowout[i * C_OUT + tid] = red[0][tid] + red[1][tid];
}

// Kernel 4: graph_out[g,c] = sum_{i in graph g} rowout[i,c]  (deterministic order)
__global__ __launch_bounds__(64) void readout_kernel(
    const float* __restrict__ rowout, const int* __restrict__ starts,
    float* __restrict__ out)
{
    const int g = blockIdx.x;
    const int tid = threadIdx.x;
    const int is = starts[g];
    const int ie = starts[g + 1];

    float acc[C_OUT] = {0.f, 0.f, 0.f, 0.f, 0.f, 0.f, 0.f, 0.f};
    for (int i = is + tid; i < ie; i += 64) {
        #pragma unroll
        for (int c = 0; c < C_OUT; ++c) acc[c] += rowout[i * C_OUT + c];
    }

    #pragma unroll
    for (int c = 0; c < C_OUT; ++c) {
        float v = acc[c];
        for (int off = 32; off; off >>= 1) v += __shfl_down(v, off);
        if (tid == 0) out[g * C_OUT + c] = v;
    }
}

extern "C" void kernel_launch(void* const* d_in, const int* in_sizes, int n_in,
                              void* d_out, int out_size, void* d_ws, size_t ws_size,
                              hipStream_t stream)
{
    const float* x    = (const float*)d_in[0];
    const float* dist = (const float*)d_in[1];
    const float* norm = (const float*)d_in[2];
    const int*   batch= (const int*)d_in[3];
    const float* fsW1 = (const float*)d_in[4];
    const float* fsb1 = (const float*)d_in[5];
    const float* fsW2 = (const float*)d_in[6];
    const float* fsb2 = (const float*)d_in[7];
    const float* rW1  = (const float*)d_in[8];
    const float* rb1  = (const float*)d_in[9];
    const float* rW2  = (const float*)d_in[10];
    const float* rb2  = (const float*)d_in[11];
    float* out = (float*)d_out;

    float* fsum   = (float*)d_ws;                       // N*C floats
    float* rowout = fsum + N_NODES * C_OUT;             // N*C floats
    int*   starts = (int*)(rowout + N_NODES * C_OUT);   // G+1 ints

    fsum_kernel<<<N_NODES, 64, 0, stream>>>(x, fsW1, fsb1, fsW2, fsb2, fsum);
    bounds_kernel<<<(N_NODES + 255) / 256, 256, 0, stream>>>(batch, starts);
    row_kernel<<<N_NODES, 128, 0, stream>>>(dist, norm, batch, starts,
                                            rW1, rb1, rW2, rb2, fsum, rowout);
    readout_kernel<<<G_NUM, 64, 0, stream>>>(rowout, starts, out);
}